// Round 8
// baseline (416.273 us; speedup 1.0000x reference)
//
#include <hip/hip_runtime.h>

// ============================================================================
// TypeNet triplet embedder — Round 8: ONE fused persistent kernel.
//   96 WGs x 512 thr (all co-resident: 96 << capacity), three phases
//   separated by device-scope atomic grid barriers:
//     phase1: LSTM1 (x staged to LDS, B-frags direct from fp32 Whh1),
//             hs1 -> global (A-frag order, WG-private), BN1 stats atomics.
//     [grid barrier]  (stats are the ONLY cross-WG data)
//     phase2: BN1 fold in-kernel (scale/shift from stats, folded W2 frags,
//             effective bias2), LSTM2 with 2-deep hs1 reg prefetch.
//     [grid barrier]
//     head:   BN2 + FC (fp16 fcW in LDS) + L2-normalize; h_last read from LDS.
//   Proven pieces kept from R7: conflict-free A-frag LDS h layout, lgkm-only
//   BAR() per step, R3 lstm_cell, 512-thr monolithic waves (VGPR ~124).
//   Safety: __syncthreads() (vmcnt drain) before barrier arrive; stats read
//   via agent-scope atomic loads; barrier counters memset each launch.
// ============================================================================

typedef __attribute__((ext_vector_type(8))) _Float16 half8;
typedef __attribute__((ext_vector_type(4))) float f32x4;

#define TS 128
#define HID 128
#define NGATE 512
#define NWG 96
#define INV_N (1.0f/65536.0f)   // 1/(B*T)

#define BAR() asm volatile("s_waitcnt lgkmcnt(0)\n\ts_barrier" ::: "memory")

__device__ __forceinline__ float rcpf(float x) { return __builtin_amdgcn_rcpf(x); }
__device__ __forceinline__ float clamp20(float x) { return fminf(fmaxf(x, -20.0f), 20.0f); }

// Fused LSTM gate elementwise (R3-proven): 5 exp + 3 rcp per element.
__device__ __forceinline__ _Float16 lstm_cell(float zi, float zf, float zg, float zo,
                                              float& c) {
  zg = clamp20(zg);
  float ei = __expf(-zi);
  float eg = __expf(-2.0f * zg);
  float ef = __expf(-zf);
  float fv = rcpf(1.0f + ef);
  float ig = (1.0f - eg) * rcpf((1.0f + ei) * (1.0f + eg));  // sigmoid(zi)*tanh(zg)
  float cc = fv * c + ig;
  c = cc;
  float ccl = clamp20(cc);
  float eo = __expf(-zo);
  float ec = __expf(-2.0f * ccl);
  float hv = (1.0f - ec) * rcpf((1.0f + eo) * (1.0f + ec));  // sigmoid(zo)*tanh(cc)
  return (_Float16)hv;
}

__device__ __forceinline__ float aload(const float* p) {
  return __hip_atomic_load(p, __ATOMIC_RELAXED, __HIP_MEMORY_SCOPE_AGENT);
}

// Device-scope grid barrier. First __syncthreads drains vmcnt (makes this
// WG's stores/atomics globally visible) per gfx950 __syncthreads semantics.
__device__ __forceinline__ void gbar(int* cnt, int* gen, int tid) {
  __syncthreads();
  if (tid == 0) {
    int g = __hip_atomic_load(gen, __ATOMIC_RELAXED, __HIP_MEMORY_SCOPE_AGENT);
    int a = __hip_atomic_fetch_add(cnt, 1, __ATOMIC_ACQ_REL, __HIP_MEMORY_SCOPE_AGENT);
    if (a == NWG - 1) {
      __hip_atomic_store(cnt, 0, __ATOMIC_RELAXED, __HIP_MEMORY_SCOPE_AGENT);
      __hip_atomic_fetch_add(gen, 1, __ATOMIC_RELEASE, __HIP_MEMORY_SCOPE_AGENT);
    } else {
      while (__hip_atomic_load(gen, __ATOMIC_ACQUIRE, __HIP_MEMORY_SCOPE_AGENT) == g)
        __builtin_amdgcn_s_sleep(2);
    }
  }
  __syncthreads();
}

// A-frag layout for a 16x128 fp16 tile:
//   addr(row,col) = (col>>5)*512 + ((col>>3)&3)*128 + row*8 + (col&7)

// ---------------------------------------------------------------------------
__global__ __launch_bounds__(512, 2) void fused_kernel(
    const float* __restrict__ xa, const float* __restrict__ xp,
    const float* __restrict__ xn,
    const float* __restrict__ Wih1, const float* __restrict__ Whh1,
    const float* __restrict__ bih1, const float* __restrict__ bhh1,
    const float* __restrict__ g1, const float* __restrict__ b1,
    const float* __restrict__ Wih2, const float* __restrict__ Whh2,
    const float* __restrict__ bih2, const float* __restrict__ bhh2,
    const float* __restrict__ g2, const float* __restrict__ b2,
    const float* __restrict__ fcW, const float* __restrict__ fcb,
    float* __restrict__ s1sum, float* __restrict__ s1sq,
    float* __restrict__ s2sum, float* __restrict__ s2sq,
    _Float16* __restrict__ hs1, int* bar_cnt, int* bar_gen,
    float* __restrict__ out) {
  const int wg = blockIdx.x;             // tile 0..95
  const int inp = wg >> 5;
  const int tid = threadIdx.x;
  const int w = tid >> 6;
  const int lane = tid & 63;
  const int l15 = lane & 15;
  const int quad = lane >> 4;
  const int col = w * 16 + l15;
  const int kb = quad * 8;

  __shared__ __align__(16) char smem[53600];
  _Float16* hb = (_Float16*)smem;        // [2][2048] fp16, 8 KB @0

  const int rbase = (quad * 16 + l15) * 8;
  const int wbase = (w >> 1) * 512 + ((w & 1) * 2 + (l15 >> 3)) * 128 +
                    quad * 32 + (l15 & 7);
  _Float16* hs1w = hs1 + (size_t)wg * TS * 2048;

  // ========================= phase 1: LSTM layer 1 =========================
  {
    _Float16* xt = (_Float16*)(smem + 8192);   // [128 t][16 r][8 d], 32 KB
    const float* x = (inp == 0) ? xa : ((inp == 1) ? xp : xn);
    const int rloc = (wg & 31) * 16;

    for (int i = tid; i < 4096; i += 512) hb[i] = (_Float16)0.0f;
    for (int i = tid; i < 16384; i += 512) xt[i] = (_Float16)0.0f;
    __syncthreads();
    for (int i = tid; i < 10240; i += 512) {
      int r = i / 640, rem = i - r * 640;
      int t = rem / 5, d = rem - t * 5;
      xt[t * 128 + r * 8 + d] = (_Float16)x[(rloc + r) * 640 + rem];
    }

    half8 bh[4][4];                      // Whh1 direct (contiguous in k)
#pragma unroll
    for (int kt = 0; kt < 4; ++kt)
#pragma unroll
      for (int gt = 0; gt < 4; ++gt) {
        const float* src = &Whh1[(gt * 128 + col) * HID + kt * 32 + kb];
        half8 v;
#pragma unroll
        for (int j = 0; j < 8; ++j) v[j] = (_Float16)src[j];
        bh[kt][gt] = v;
      }
    half8 bx[4];                         // Wih1 K=32-padded (quad0, j<5)
#pragma unroll
    for (int gt = 0; gt < 4; ++gt) {
      half8 v = {0, 0, 0, 0, 0, 0, 0, 0};
      if (quad == 0) {
#pragma unroll
        for (int j = 0; j < 5; ++j) v[j] = (_Float16)Wih1[(gt * 128 + col) * 5 + j];
      }
      bx[gt] = v;
    }
    f32x4 biasv[4];
#pragma unroll
    for (int gt = 0; gt < 4; ++gt) {
      float b = bih1[gt * 128 + col] + bhh1[gt * 128 + col];
      biasv[gt][0] = b; biasv[gt][1] = b; biasv[gt][2] = b; biasv[gt][3] = b;
    }

    float c[4] = {0, 0, 0, 0};
    float ssum = 0.0f, ssq = 0.0f;
    __syncthreads();                     // xt + hb ready

    half8 xv = {0, 0, 0, 0, 0, 0, 0, 0};
    if (quad == 0) xv = *(const half8*)&xt[l15 * 8];

    for (int t = 0; t < TS; ++t) {
      f32x4 acc[4];
#pragma unroll
      for (int gt = 0; gt < 4; ++gt)
        acc[gt] = __builtin_amdgcn_mfma_f32_16x16x32_f16(xv, bx[gt], biasv[gt], 0, 0, 0);
      if (t + 1 < TS && quad == 0)
        xv = *(const half8*)&xt[(t + 1) * 128 + l15 * 8];
      BAR();                             // h(t-1) visible
      if (t > 0) {                       // coalesced h(t-1) -> hs1
        float2 cp = *(const float2*)&hb[(t & 1) * 2048 + tid * 4];
        *(float2*)&hs1w[(size_t)(t - 1) * 2048 + tid * 4] = cp;
      }
#pragma unroll
      for (int kt = 0; kt < 4; ++kt) {   // conflict-free b128 reads
        half8 ah = *(const half8*)&hb[(t & 1) * 2048 + kt * 512 + rbase];
#pragma unroll
        for (int gt = 0; gt < 4; ++gt)
          acc[gt] = __builtin_amdgcn_mfma_f32_16x16x32_f16(ah, bh[kt][gt], acc[gt], 0, 0, 0);
      }
      const int wb = (t + 1) & 1;
#pragma unroll
      for (int r = 0; r < 4; ++r) {
        _Float16 hh = lstm_cell(acc[0][r], acc[1][r], acc[2][r], acc[3][r], c[r]);
        float hr = (float)hh;
        ssum += hr; ssq += hr * hr;
        hb[wb * 2048 + wbase + r * 8] = hh;
      }
    }
    BAR();                               // h(127) visible
    {
      float2 cp = *(const float2*)&hb[tid * 4];  // buffer 0
      *(float2*)&hs1w[(size_t)(TS - 1) * 2048 + tid * 4] = cp;
    }
    float s = ssum, q = ssq;
    s += __shfl_xor(s, 16); s += __shfl_xor(s, 32);
    q += __shfl_xor(q, 16); q += __shfl_xor(q, 32);
    if (quad == 0) {
      atomicAdd(&s1sum[inp * HID + col], s);
      atomicAdd(&s1sq[inp * HID + col], q);
    }
  }

  gbar(bar_cnt, bar_gen, tid);           // ---- BN1 stats complete ----

  // ========================= phase 2: LSTM layer 2 =========================
  {
    float* scale1L = (float*)(smem + 8192);   // [128]
    float* shift1L = (float*)(smem + 8704);   // [128]
    if (tid < 128) {
      float sm = aload(&s1sum[inp * HID + tid]);
      float sq = aload(&s1sq[inp * HID + tid]);
      float m = sm * INV_N;
      float v = sq * INV_N - m * m;
      float sc = g1[tid] * rsqrtf(v + 1e-5f);
      scale1L[tid] = sc;
      shift1L[tid] = b1[tid] - m * sc;
    }
    for (int i = tid; i < 4096; i += 512) hb[i] = (_Float16)0.0f;
    __syncthreads();                     // scale/shift + hb-zero ready

    half8 bh[4][4], bxw[4][4];           // Whh2 direct; W2 folded with BN1 scale
#pragma unroll
    for (int kt = 0; kt < 4; ++kt)
#pragma unroll
      for (int gt = 0; gt < 4; ++gt) {
        const float* ph = &Whh2[(gt * 128 + col) * HID + kt * 32 + kb];
        const float* px = &Wih2[(gt * 128 + col) * HID + kt * 32 + kb];
        half8 vh, vx;
#pragma unroll
        for (int j = 0; j < 8; ++j) {
          vh[j] = (_Float16)ph[j];
          vx[j] = (_Float16)(scale1L[kt * 32 + kb + j] * px[j]);
        }
        bh[kt][gt] = vh;
        bxw[kt][gt] = vx;
      }
    f32x4 biasv[4];
#pragma unroll
    for (int gt = 0; gt < 4; ++gt) {
      int gcol = gt * 128 + col;
      float b = bih2[gcol] + bhh2[gcol];
      const float* pw = &Wih2[gcol * HID];
      for (int h = 0; h < HID; ++h) b += shift1L[h] * pw[h];
      biasv[gt][0] = b; biasv[gt][1] = b; biasv[gt][2] = b; biasv[gt][3] = b;
    }

    half8 a2A[4], a2B[4];                // 2-deep hs1 prefetch
#pragma unroll
    for (int kt = 0; kt < 4; ++kt) {
      a2A[kt] = *(const half8*)&hs1w[kt * 512 + rbase];
      a2B[kt] = *(const half8*)&hs1w[(size_t)2048 + kt * 512 + rbase];
    }

    float c[4] = {0, 0, 0, 0};
    float ssum = 0.0f, ssq = 0.0f;

    auto step = [&](int t, half8 (&cur)[4]) {
      f32x4 acc[4];
#pragma unroll
      for (int gt = 0; gt < 4; ++gt)
        acc[gt] = __builtin_amdgcn_mfma_f32_16x16x32_f16(cur[0], bxw[0][gt], biasv[gt], 0, 0, 0);
#pragma unroll
      for (int kt = 1; kt < 4; ++kt)
#pragma unroll
        for (int gt = 0; gt < 4; ++gt)
          acc[gt] = __builtin_amdgcn_mfma_f32_16x16x32_f16(cur[kt], bxw[kt][gt], acc[gt], 0, 0, 0);
      if (t + 2 < TS) {
#pragma unroll
        for (int kt = 0; kt < 4; ++kt)
          cur[kt] = *(const half8*)&hs1w[(size_t)(t + 2) * 2048 + kt * 512 + rbase];
      }
      BAR();                             // h(t-1) visible
#pragma unroll
      for (int kt = 0; kt < 4; ++kt) {
        half8 ah = *(const half8*)&hb[(t & 1) * 2048 + kt * 512 + rbase];
#pragma unroll
        for (int gt = 0; gt < 4; ++gt)
          acc[gt] = __builtin_amdgcn_mfma_f32_16x16x32_f16(ah, bh[kt][gt], acc[gt], 0, 0, 0);
      }
      const int wb = (t + 1) & 1;
#pragma unroll
      for (int r = 0; r < 4; ++r) {
        _Float16 hh = lstm_cell(acc[0][r], acc[1][r], acc[2][r], acc[3][r], c[r]);
        float hr = (float)hh;
        ssum += hr; ssq += hr * hr;
        hb[wb * 2048 + wbase + r * 8] = hh;   // h(127) lands in buffer 0
      }
    };

    for (int t = 0; t < TS; t += 2) {
      step(t, a2A);
      step(t + 1, a2B);
    }

    float s = ssum, q = ssq;
    s += __shfl_xor(s, 16); s += __shfl_xor(s, 32);
    q += __shfl_xor(q, 16); q += __shfl_xor(q, 32);
    if (quad == 0) {
      atomicAdd(&s2sum[inp * HID + col], s);
      atomicAdd(&s2sq[inp * HID + col], q);
    }
  }

  gbar(bar_cnt, bar_gen, tid);           // ---- BN2 stats complete ----

  // ============================ head phase ============================
  {
    _Float16* fcwT = (_Float16*)(smem + 8192);  // [128 h][136 j] fp16
    float* bnh  = (float*)(smem + 43008);       // [16][132]
    float* s2L  = (float*)(smem + 51456);       // [128]
    float* sh2L = (float*)(smem + 51968);       // [128]
    float* part = (float*)(smem + 52480);       // [16][16]
    float* invv = (float*)(smem + 53504);       // [16]

    if (tid < 128) {
      float sm = aload(&s2sum[inp * HID + tid]);
      float sq = aload(&s2sq[inp * HID + tid]);
      float m = sm * INV_N;
      float v = sq * INV_N - m * m;
      float sc = g2[tid] * rsqrtf(v + 1e-5f);
      s2L[tid] = sc;
      sh2L[tid] = b2[tid] - m * sc;
    }
    for (int i = tid; i < 16384; i += 512) {
      int j = i >> 7, h = i & 127;
      fcwT[h * 136 + j] = (_Float16)fcW[i];
    }
    __syncthreads();
    const int row = (tid & 255) >> 4, jl = tid & 15;
    if (tid < 256) {                     // bnh from hb[0] (A-frag layout)
      int c0 = jl * 8;
#pragma unroll
      for (int k = 0; k < 8; ++k) {
        int h = c0 + k;
        int ad = ((h >> 5) << 9) + (((h >> 3) & 3) << 7) + (row << 3) + (h & 7);
        bnh[row * 132 + h] = (float)hb[ad] * s2L[h] + sh2L[h];
      }
    }
    __syncthreads();
    float emb[8];
    if (tid < 256) {
      float sq = 0.0f;
#pragma unroll
      for (int jj = 0; jj < 8; ++jj) {
        int j = jl + jj * 16;
        float acc = fcb[j];
        for (int h = 0; h < HID; ++h) acc += bnh[row * 132 + h] * (float)fcwT[h * 136 + j];
        emb[jj] = acc; sq += acc * acc;
      }
      part[row * 16 + jl] = sq;
    }
    __syncthreads();
    if (tid < 16) {
      float s = 0.0f;
      for (int k = 0; k < 16; ++k) s += part[tid * 16 + k];
      invv[tid] = 1.0f / fmaxf(sqrtf(s), 1e-12f);
    }
    __syncthreads();
    if (tid < 256) {
#pragma unroll
      for (int jj = 0; jj < 8; ++jj)
        out[(size_t)(wg * 16 + row) * HID + jl + jj * 16] = emb[jj] * invv[row];
    }
  }
}

// ---------------------------------------------------------------------------
extern "C" void kernel_launch(void* const* d_in, const int* in_sizes, int n_in,
                              void* d_out, int out_size, void* d_ws, size_t ws_size,
                              hipStream_t stream) {
  const float* a    = (const float*)d_in[0];
  const float* p    = (const float*)d_in[1];
  const float* nn   = (const float*)d_in[2];
  const float* Wih1 = (const float*)d_in[3];
  const float* Whh1 = (const float*)d_in[4];
  const float* bih1 = (const float*)d_in[5];
  const float* bhh1 = (const float*)d_in[6];
  const float* g1   = (const float*)d_in[7];
  const float* b1   = (const float*)d_in[8];
  const float* Wih2 = (const float*)d_in[9];
  const float* Whh2 = (const float*)d_in[10];
  const float* bih2 = (const float*)d_in[11];
  const float* bhh2 = (const float*)d_in[12];
  const float* g2   = (const float*)d_in[13];
  const float* b2   = (const float*)d_in[14];
  const float* fcW  = (const float*)d_in[15];
  const float* fcb  = (const float*)d_in[16];

  char* ws = (char*)d_ws;
  float* s1sum = (float*)(ws + 0);       // 384 f32 = 1536B
  float* s1sq  = (float*)(ws + 1536);
  float* s2sum = (float*)(ws + 3072);
  float* s2sq  = (float*)(ws + 4608);    // ends @6144
  int* bar_cnt = (int*)(ws + 6144);
  int* bar_gen = (int*)(ws + 6148);
  _Float16* hs1 = (_Float16*)(ws + 8192);  // 50331648B -> ~50.3MB total

  hipMemsetAsync(ws, 0, 6656, stream);   // stats + barrier state

  fused_kernel<<<NWG, 512, 0, stream>>>(
      a, p, nn, Wih1, Whh1, bih1, bhh1, g1, b1,
      Wih2, Whh2, bih2, bhh2, g2, b2, fcW, fcb,
      s1sum, s1sq, s2sum, s2sq, hs1, bar_cnt, bar_gen, (float*)d_out);
}

// Round 9
// 407.505 us; speedup vs baseline: 1.0215x; 1.0215x over previous
//
#include <hip/hip_runtime.h>

// ============================================================================
// TypeNet triplet embedder — Round 9: 3 launches (prep/mid folded in-kernel).
//   lstm1: in-kernel prep (fp32->fp16 weight frags), x->LDS, step loop,
//          hs1 out (A-frag order), BN1 stats atomics.
//   lstm2: BN1 fold at kernel start (stats via kernel-boundary sync),
//          folded-W2 frags + effective bias2, step loop w/ 2-deep prefetch,
//          h_last out as A-frag cooperative copy, BN2 stats atomics.
//   head:  BN2 + FC + L2-normalize (reads A-frag h_last).
//   Step-loop structure is R7-proven: conflict-free A-frag LDS h layout,
//   one lgkm-only BAR per step, R3 lstm_cell, 512-thr monolithic waves.
// ============================================================================

typedef __attribute__((ext_vector_type(8))) _Float16 half8;
typedef __attribute__((ext_vector_type(4))) float f32x4;

#define TS 128
#define HID 128
#define NGATE 512
#define INV_N (1.0f/65536.0f)   // 1/(B*T)

#define BAR() asm volatile("s_waitcnt lgkmcnt(0)\n\ts_barrier" ::: "memory")

__device__ __forceinline__ float rcpf(float x) { return __builtin_amdgcn_rcpf(x); }
__device__ __forceinline__ float clamp20(float x) { return fminf(fmaxf(x, -20.0f), 20.0f); }

// Fused LSTM gate elementwise (R3-proven): 5 exp + 3 rcp per element.
__device__ __forceinline__ _Float16 lstm_cell(float zi, float zf, float zg, float zo,
                                              float& c) {
  zg = clamp20(zg);
  float ei = __expf(-zi);
  float eg = __expf(-2.0f * zg);
  float ef = __expf(-zf);
  float fv = rcpf(1.0f + ef);
  float ig = (1.0f - eg) * rcpf((1.0f + ei) * (1.0f + eg));  // sigmoid(zi)*tanh(zg)
  float cc = fv * c + ig;
  c = cc;
  float ccl = clamp20(cc);
  float eo = __expf(-zo);
  float ec = __expf(-2.0f * ccl);
  float hv = (1.0f - ec) * rcpf((1.0f + eo) * (1.0f + ec));  // sigmoid(zo)*tanh(cc)
  return (_Float16)hv;
}

// A-frag layout for a 16x128 fp16 tile:
//   addr(row,col) = (col>>5)*512 + ((col>>3)&3)*128 + row*8 + (col&7)
// Reader lane (row=l15, k=kt*32+quad*8+j): base = kt*512 + (quad*16+l15)*8.

// ---------------------------------------------------------------------------
// LSTM layer 1. 96 WGs x 512. hs1: [96 tile][128 t][2048] A-frag order.
// ---------------------------------------------------------------------------
__global__ __launch_bounds__(512, 2) void lstm1_kernel(
    const float* __restrict__ xa, const float* __restrict__ xp,
    const float* __restrict__ xn,
    const float* __restrict__ Wih1, const float* __restrict__ Whh1,
    const float* __restrict__ bih1, const float* __restrict__ bhh1,
    _Float16* __restrict__ hs1,
    float* __restrict__ s1sum, float* __restrict__ s1sq) {
  const int wg = blockIdx.x;             // tile 0..95
  const int inp = wg >> 5;
  const int tid = threadIdx.x;
  const int w = tid >> 6;
  const int lane = tid & 63;
  const int l15 = lane & 15;
  const int quad = lane >> 4;
  const int col = w * 16 + l15;
  const int kb = quad * 8;

  __shared__ _Float16 hb[2][2048];       // double-buffered h, A-frag order
  __shared__ _Float16 xt[TS][128];       // [t][16 r * 8 d], K-padded, 32 KB

  const float* x = (inp == 0) ? xa : ((inp == 1) ? xp : xn);
  const int rloc = (wg & 31) * 16;

  for (int i = tid; i < 4096; i += 512) ((_Float16*)hb)[i] = (_Float16)0.0f;
  for (int i = tid; i < TS * 128; i += 512) ((_Float16*)xt)[i] = (_Float16)0.0f;
  __syncthreads();
  for (int i = tid; i < 10240; i += 512) {
    int r = i / 640, rem = i - r * 640;
    int t = rem / 5, d = rem - t * 5;
    xt[t][r * 8 + d] = (_Float16)x[(rloc + r) * 640 + rem];
  }

  half8 bh[4][4];                        // Whh1 direct fp32->fp16 (rows contiguous)
#pragma unroll
  for (int kt = 0; kt < 4; ++kt)
#pragma unroll
    for (int gt = 0; gt < 4; ++gt) {
      const float* src = &Whh1[(gt * 128 + col) * HID + kt * 32 + kb];
      half8 v;
#pragma unroll
      for (int j = 0; j < 8; ++j) v[j] = (_Float16)src[j];
      bh[kt][gt] = v;
    }
  half8 bx[4];                           // Wih1 K=32-padded (quad0, j<5)
#pragma unroll
  for (int gt = 0; gt < 4; ++gt) {
    half8 v = {0, 0, 0, 0, 0, 0, 0, 0};
    if (quad == 0) {
#pragma unroll
      for (int j = 0; j < 5; ++j) v[j] = (_Float16)Wih1[(gt * 128 + col) * 5 + j];
    }
    bx[gt] = v;
  }
  f32x4 biasv[4];
#pragma unroll
  for (int gt = 0; gt < 4; ++gt) {
    float b = bih1[gt * 128 + col] + bhh1[gt * 128 + col];
    biasv[gt][0] = b; biasv[gt][1] = b; biasv[gt][2] = b; biasv[gt][3] = b;
  }

  const int rbase = (quad * 16 + l15) * 8;
  const int wbase = (w >> 1) * 512 + ((w & 1) * 2 + (l15 >> 3)) * 128 +
                    quad * 32 + (l15 & 7);
  _Float16* hs1w = hs1 + (size_t)wg * TS * 2048;

  float c[4] = {0, 0, 0, 0};
  float ssum = 0.0f, ssq = 0.0f;
  __syncthreads();                       // xt + hb ready

  half8 xv = {0, 0, 0, 0, 0, 0, 0, 0};
  if (quad == 0) xv = *(const half8*)&xt[0][l15 * 8];

  for (int t = 0; t < TS; ++t) {
    f32x4 acc[4];
#pragma unroll
    for (int gt = 0; gt < 4; ++gt)
      acc[gt] = __builtin_amdgcn_mfma_f32_16x16x32_f16(xv, bx[gt], biasv[gt], 0, 0, 0);
    if (t + 1 < TS && quad == 0)
      xv = *(const half8*)&xt[t + 1][l15 * 8];
    BAR();                               // h(t-1) visible
    if (t > 0) {                         // coalesced h(t-1) -> hs1
      float2 cp = *(const float2*)&hb[t & 1][tid * 4];
      *(float2*)&hs1w[(size_t)(t - 1) * 2048 + tid * 4] = cp;
    }
#pragma unroll
    for (int kt = 0; kt < 4; ++kt) {     // conflict-free b128 reads
      half8 ah = *(const half8*)&hb[t & 1][kt * 512 + rbase];
#pragma unroll
      for (int gt = 0; gt < 4; ++gt)
        acc[gt] = __builtin_amdgcn_mfma_f32_16x16x32_f16(ah, bh[kt][gt], acc[gt], 0, 0, 0);
    }
    const int wb = (t + 1) & 1;
#pragma unroll
    for (int r = 0; r < 4; ++r) {
      _Float16 hh = lstm_cell(acc[0][r], acc[1][r], acc[2][r], acc[3][r], c[r]);
      float hr = (float)hh;
      ssum += hr; ssq += hr * hr;
      hb[wb][wbase + r * 8] = hh;
    }
  }
  BAR();                                 // h(127) visible
  {
    float2 cp = *(const float2*)&hb[0][tid * 4];
    *(float2*)&hs1w[(size_t)(TS - 1) * 2048 + tid * 4] = cp;
  }
  float s = ssum, q = ssq;
  s += __shfl_xor(s, 16); s += __shfl_xor(s, 32);
  q += __shfl_xor(q, 16); q += __shfl_xor(q, 32);
  if (quad == 0) {
    atomicAdd(&s1sum[inp * HID + col], s);
    atomicAdd(&s1sq[inp * HID + col], q);
  }
}

// ---------------------------------------------------------------------------
// LSTM layer 2. BN1 fold in-kernel; h_last out in A-frag order per tile.
// ---------------------------------------------------------------------------
__global__ __launch_bounds__(512, 2) void lstm2_kernel(
    const _Float16* __restrict__ hs1,    // [96][128][2048] A-frag order
    const float* __restrict__ Wih2, const float* __restrict__ Whh2,
    const float* __restrict__ bih2, const float* __restrict__ bhh2,
    const float* __restrict__ g1, const float* __restrict__ b1,
    const float* __restrict__ s1sum, const float* __restrict__ s1sq,
    _Float16* __restrict__ hlast,        // [96][2048] A-frag order
    float* __restrict__ s2sum, float* __restrict__ s2sq) {
  const int wg = blockIdx.x;             // tile 0..95
  const int inp = wg >> 5;
  const int tid = threadIdx.x;
  const int w = tid >> 6;
  const int lane = tid & 63;
  const int l15 = lane & 15;
  const int quad = lane >> 4;
  const int col = w * 16 + l15;
  const int kb = quad * 8;

  __shared__ _Float16 hb[2][2048];
  __shared__ float scale1L[128], shift1L[128];

  if (tid < 128) {
    float sm = s1sum[inp * HID + tid];
    float sq = s1sq[inp * HID + tid];
    float m = sm * INV_N;
    float v = sq * INV_N - m * m;
    float sc = g1[tid] * rsqrtf(v + 1e-5f);
    scale1L[tid] = sc;
    shift1L[tid] = b1[tid] - m * sc;
  }
  for (int i = tid; i < 4096; i += 512) ((_Float16*)hb)[i] = (_Float16)0.0f;
  __syncthreads();                       // scale/shift + hb-zero ready

  half8 bh[4][4], bxw[4][4];             // Whh2 direct; W2 folded with BN1 scale
#pragma unroll
  for (int kt = 0; kt < 4; ++kt)
#pragma unroll
    for (int gt = 0; gt < 4; ++gt) {
      const float* ph = &Whh2[(gt * 128 + col) * HID + kt * 32 + kb];
      const float* px = &Wih2[(gt * 128 + col) * HID + kt * 32 + kb];
      half8 vh, vx;
#pragma unroll
      for (int j = 0; j < 8; ++j) {
        vh[j] = (_Float16)ph[j];
        vx[j] = (_Float16)(scale1L[kt * 32 + kb + j] * px[j]);
      }
      bh[kt][gt] = vh;
      bxw[kt][gt] = vx;
    }
  f32x4 biasv[4];
#pragma unroll
  for (int gt = 0; gt < 4; ++gt) {
    int gcol = gt * 128 + col;
    float b = bih2[gcol] + bhh2[gcol];
    const float* pw = &Wih2[gcol * HID];
    for (int h = 0; h < HID; ++h) b += shift1L[h] * pw[h];
    biasv[gt][0] = b; biasv[gt][1] = b; biasv[gt][2] = b; biasv[gt][3] = b;
  }

  const int rbase = (quad * 16 + l15) * 8;
  const int wbase = (w >> 1) * 512 + ((w & 1) * 2 + (l15 >> 3)) * 128 +
                    quad * 32 + (l15 & 7);
  const _Float16* hg = hs1 + (size_t)wg * TS * 2048;

  half8 a2A[4], a2B[4];                  // 2-deep hs1 prefetch (coalesced 16B)
#pragma unroll
  for (int kt = 0; kt < 4; ++kt) {
    a2A[kt] = *(const half8*)&hg[kt * 512 + rbase];
    a2B[kt] = *(const half8*)&hg[(size_t)2048 + kt * 512 + rbase];
  }

  float c[4] = {0, 0, 0, 0};
  float ssum = 0.0f, ssq = 0.0f;

  auto step = [&](int t, half8 (&cur)[4]) {
    f32x4 acc[4];
#pragma unroll
    for (int gt = 0; gt < 4; ++gt)
      acc[gt] = __builtin_amdgcn_mfma_f32_16x16x32_f16(cur[0], bxw[0][gt], biasv[gt], 0, 0, 0);
#pragma unroll
    for (int kt = 1; kt < 4; ++kt)
#pragma unroll
      for (int gt = 0; gt < 4; ++gt)
        acc[gt] = __builtin_amdgcn_mfma_f32_16x16x32_f16(cur[kt], bxw[kt][gt], acc[gt], 0, 0, 0);
    if (t + 2 < TS) {                    // prefetch t+2 into regs just consumed
#pragma unroll
      for (int kt = 0; kt < 4; ++kt)
        cur[kt] = *(const half8*)&hg[(size_t)(t + 2) * 2048 + kt * 512 + rbase];
    }
    BAR();                               // h(t-1) visible; vmcnt untouched
#pragma unroll
    for (int kt = 0; kt < 4; ++kt) {
      half8 ah = *(const half8*)&hb[t & 1][kt * 512 + rbase];
#pragma unroll
      for (int gt = 0; gt < 4; ++gt)
        acc[gt] = __builtin_amdgcn_mfma_f32_16x16x32_f16(ah, bh[kt][gt], acc[gt], 0, 0, 0);
    }
    const int wb = (t + 1) & 1;
#pragma unroll
    for (int r = 0; r < 4; ++r) {
      _Float16 hh = lstm_cell(acc[0][r], acc[1][r], acc[2][r], acc[3][r], c[r]);
      float hr = (float)hh;
      ssum += hr; ssq += hr * hr;
      hb[wb][wbase + r * 8] = hh;        // h(127) lands in buffer 0
    }
  };

  for (int t = 0; t < TS; t += 2) {
    step(t, a2A);
    step(t + 1, a2B);
  }

  BAR();                                 // h(127) writes visible
  {
    float2 cp = *(const float2*)&hb[0][tid * 4];
    *(float2*)&hlast[(size_t)wg * 2048 + tid * 4] = cp;
  }
  float s = ssum, q = ssq;
  s += __shfl_xor(s, 16); s += __shfl_xor(s, 32);
  q += __shfl_xor(q, 16); q += __shfl_xor(q, 32);
  if (quad == 0) {
    atomicAdd(&s2sum[inp * HID + col], s);
    atomicAdd(&s2sq[inp * HID + col], q);
  }
}

// ---------------------------------------------------------------------------
// Head: BN2 finalize + FC + L2 normalize. 96 WGs x 256. hlast is A-frag.
// ---------------------------------------------------------------------------
__global__ __launch_bounds__(256, 1) void head_kernel(
    const _Float16* __restrict__ hlast,  // [96][2048] A-frag order
    const float* __restrict__ s2sum, const float* __restrict__ s2sq,
    const float* __restrict__ g2, const float* __restrict__ b2,
    const float* __restrict__ fcW, const float* __restrict__ fcb,
    float* __restrict__ out) {
  const int wg = blockIdx.x;
  const int inp = wg >> 5;
  const int gr0 = wg * 16;
  const int tid = threadIdx.x;

  __shared__ float fcwT[128][132];       // fcwT[h][j] = fcW[j][h]
  __shared__ float bnh[16][132];
  __shared__ float s2[128], sh2[128];
  __shared__ float part[16][16];
  __shared__ float inv[16];

  if (tid < 128) {
    float m = s2sum[inp * HID + tid] * INV_N;
    float v = s2sq[inp * HID + tid] * INV_N - m * m;
    float s = g2[tid] * rsqrtf(v + 1e-5f);
    s2[tid] = s; sh2[tid] = b2[tid] - m * s;
  }
  for (int i = tid; i < 16384; i += 256) {
    int j = i >> 7, h = i & 127;
    fcwT[h][j] = fcW[i];
  }
  __syncthreads();
  {
    int row = tid >> 4, c0 = (tid & 15) * 8;
#pragma unroll
    for (int k = 0; k < 8; ++k) {
      int h = c0 + k;
      int ad = ((h >> 5) << 9) + (((h >> 3) & 3) << 7) + (row << 3) + (h & 7);
      bnh[row][h] = (float)hlast[(size_t)wg * 2048 + ad] * s2[h] + sh2[h];
    }
  }
  __syncthreads();
  const int row = tid >> 4, jl = tid & 15;
  float emb[8];
  float sq = 0.0f;
#pragma unroll
  for (int jj = 0; jj < 8; ++jj) {
    int j = jl + jj * 16;
    float acc = fcb[j];
    for (int h = 0; h < HID; ++h) acc += bnh[row][h] * fcwT[h][j];
    emb[jj] = acc; sq += acc * acc;
  }
  part[row][jl] = sq;
  __syncthreads();
  if (tid < 16) {
    float s = 0.0f;
    for (int k = 0; k < 16; ++k) s += part[tid][k];
    inv[tid] = 1.0f / fmaxf(sqrtf(s), 1e-12f);
  }
  __syncthreads();
#pragma unroll
  for (int jj = 0; jj < 8; ++jj)
    out[(size_t)(gr0 + row) * HID + jl + jj * 16] = emb[jj] * inv[row];
}

// ---------------------------------------------------------------------------
extern "C" void kernel_launch(void* const* d_in, const int* in_sizes, int n_in,
                              void* d_out, int out_size, void* d_ws, size_t ws_size,
                              hipStream_t stream) {
  const float* a    = (const float*)d_in[0];
  const float* p    = (const float*)d_in[1];
  const float* nn   = (const float*)d_in[2];
  const float* Wih1 = (const float*)d_in[3];
  const float* Whh1 = (const float*)d_in[4];
  const float* bih1 = (const float*)d_in[5];
  const float* bhh1 = (const float*)d_in[6];
  const float* g1   = (const float*)d_in[7];
  const float* b1   = (const float*)d_in[8];
  const float* Wih2 = (const float*)d_in[9];
  const float* Whh2 = (const float*)d_in[10];
  const float* bih2 = (const float*)d_in[11];
  const float* bhh2 = (const float*)d_in[12];
  const float* g2   = (const float*)d_in[13];
  const float* b2   = (const float*)d_in[14];
  const float* fcW  = (const float*)d_in[15];
  const float* fcb  = (const float*)d_in[16];

  char* ws = (char*)d_ws;
  float* s1sum = (float*)(ws + 0);       // 384 f32 = 1536B
  float* s1sq  = (float*)(ws + 1536);
  float* s2sum = (float*)(ws + 3072);
  float* s2sq  = (float*)(ws + 4608);    // ends @6144
  _Float16* hlast = (_Float16*)(ws + 8192);    // 393216B -> @401408
  _Float16* hs1   = (_Float16*)(ws + 401408);  // 50331648B -> ~50.7MB total

  hipMemsetAsync(ws, 0, 6144, stream);   // zero BN stats accumulators

  lstm1_kernel<<<96, 512, 0, stream>>>(a, p, nn, Wih1, Whh1, bih1, bhh1,
                                       hs1, s1sum, s1sq);
  lstm2_kernel<<<96, 512, 0, stream>>>(hs1, Wih2, Whh2, bih2, bhh2, g1, b1,
                                       s1sum, s1sq, hlast, s2sum, s2sq);
  head_kernel<<<96, 256, 0, stream>>>(hlast, s2sum, s2sq, g2, b2, fcW, fcb,
                                      (float*)d_out);
}

// Round 11
// 375.117 us; speedup vs baseline: 1.1097x; 1.0863x over previous
//
#include <hip/hip_runtime.h>

// ============================================================================
// TypeNet triplet embedder — Round 11: R10 structure with a DETERMINISTIC,
// poison-proof stats path (no atomics, no workspace memset).
//   lstm1: in-kernel prep, hs1 out (A-frag), per-WG BN1 partials (plain stores).
//   mid:   reduces partials; w2s = BN1-folded Wih2 (fp16) + bias2eff.
//   lstm2: R7-proven step loop; per-WG BN2 partials.
//   head:  reduces BN2 partials; BN2 + FC + L2-normalize.
//   Invariants: conflict-free A-frag LDS h layout, one lgkm-only BAR/step,
//   R3 lstm_cell, 512-thr monolithic waves. Every ws byte used is written
//   before read within the same launch (harness re-poisons ws to 0xAA).
// ============================================================================

typedef __attribute__((ext_vector_type(8))) _Float16 half8;
typedef __attribute__((ext_vector_type(4))) float f32x4;

#define TS 128
#define HID 128
#define NGATE 512
#define INV_N (1.0f/65536.0f)   // 1/(B*T)

#define BAR() asm volatile("s_waitcnt lgkmcnt(0)\n\ts_barrier" ::: "memory")

__device__ __forceinline__ float rcpf(float x) { return __builtin_amdgcn_rcpf(x); }
__device__ __forceinline__ float clamp20(float x) { return fminf(fmaxf(x, -20.0f), 20.0f); }

// Fused LSTM gate elementwise (R3-proven): 5 exp + 3 rcp per element.
__device__ __forceinline__ _Float16 lstm_cell(float zi, float zf, float zg, float zo,
                                              float& c) {
  zg = clamp20(zg);
  float ei = __expf(-zi);
  float eg = __expf(-2.0f * zg);
  float ef = __expf(-zf);
  float fv = rcpf(1.0f + ef);
  float ig = (1.0f - eg) * rcpf((1.0f + ei) * (1.0f + eg));  // sigmoid(zi)*tanh(zg)
  float cc = fv * c + ig;
  c = cc;
  float ccl = clamp20(cc);
  float eo = __expf(-zo);
  float ec = __expf(-2.0f * ccl);
  float hv = (1.0f - ec) * rcpf((1.0f + eo) * (1.0f + ec));  // sigmoid(zo)*tanh(cc)
  return (_Float16)hv;
}

// A-frag layout for a 16x128 fp16 tile:
//   addr(row,col) = (col>>5)*512 + ((col>>3)&3)*128 + row*8 + (col&7)
// Reader lane (row=l15, k=kt*32+quad*8+j): base = kt*512 + (quad*16+l15)*8.

// ---------------------------------------------------------------------------
// LSTM layer 1. 96 WGs x 512. hs1: [96 tile][128 t][2048] A-frag order.
// BN1 partials: s1part/s1qpart[96][128] (per-WG, no atomics).
// ---------------------------------------------------------------------------
__global__ __launch_bounds__(512, 2) void lstm1_kernel(
    const float* __restrict__ xa, const float* __restrict__ xp,
    const float* __restrict__ xn,
    const float* __restrict__ Wih1, const float* __restrict__ Whh1,
    const float* __restrict__ bih1, const float* __restrict__ bhh1,
    _Float16* __restrict__ hs1,
    float* __restrict__ s1part, float* __restrict__ s1qpart) {
  const int wg = blockIdx.x;             // tile 0..95
  const int inp = wg >> 5;
  const int tid = threadIdx.x;
  const int w = tid >> 6;
  const int lane = tid & 63;
  const int l15 = lane & 15;
  const int quad = lane >> 4;
  const int col = w * 16 + l15;
  const int kb = quad * 8;

  __shared__ _Float16 hb[2][2048];       // double-buffered h, A-frag order
  __shared__ _Float16 xt[TS][128];       // [t][16 r * 8 d], K-padded, 32 KB

  const float* x = (inp == 0) ? xa : ((inp == 1) ? xp : xn);
  const int rloc = (wg & 31) * 16;

  for (int i = tid; i < 4096; i += 512) ((_Float16*)hb)[i] = (_Float16)0.0f;
  for (int i = tid; i < TS * 128; i += 512) ((_Float16*)xt)[i] = (_Float16)0.0f;
  __syncthreads();
  for (int i = tid; i < 10240; i += 512) {
    int r = i / 640, rem = i - r * 640;
    int t = rem / 5, d = rem - t * 5;
    xt[t][r * 8 + d] = (_Float16)x[(rloc + r) * 640 + rem];
  }

  half8 bh[4][4];                        // Whh1 direct fp32->fp16 (rows contiguous)
#pragma unroll
  for (int kt = 0; kt < 4; ++kt)
#pragma unroll
    for (int gt = 0; gt < 4; ++gt) {
      const float* src = &Whh1[(gt * 128 + col) * HID + kt * 32 + kb];
      half8 v;
#pragma unroll
      for (int j = 0; j < 8; ++j) v[j] = (_Float16)src[j];
      bh[kt][gt] = v;
    }
  half8 bx[4];                           // Wih1 K=32-padded (quad0, j<5)
#pragma unroll
  for (int gt = 0; gt < 4; ++gt) {
    half8 v = {0, 0, 0, 0, 0, 0, 0, 0};
    if (quad == 0) {
#pragma unroll
      for (int j = 0; j < 5; ++j) v[j] = (_Float16)Wih1[(gt * 128 + col) * 5 + j];
    }
    bx[gt] = v;
  }
  f32x4 biasv[4];
#pragma unroll
  for (int gt = 0; gt < 4; ++gt) {
    float b = bih1[gt * 128 + col] + bhh1[gt * 128 + col];
    biasv[gt][0] = b; biasv[gt][1] = b; biasv[gt][2] = b; biasv[gt][3] = b;
  }

  const int rbase = (quad * 16 + l15) * 8;
  const int wbase = (w >> 1) * 512 + ((w & 1) * 2 + (l15 >> 3)) * 128 +
                    quad * 32 + (l15 & 7);
  _Float16* hs1w = hs1 + (size_t)wg * TS * 2048;

  float c[4] = {0, 0, 0, 0};
  float ssum = 0.0f, ssq = 0.0f;
  __syncthreads();                       // xt + hb ready

  half8 xv = {0, 0, 0, 0, 0, 0, 0, 0};
  if (quad == 0) xv = *(const half8*)&xt[0][l15 * 8];

  for (int t = 0; t < TS; ++t) {
    f32x4 acc[4];
#pragma unroll
    for (int gt = 0; gt < 4; ++gt)
      acc[gt] = __builtin_amdgcn_mfma_f32_16x16x32_f16(xv, bx[gt], biasv[gt], 0, 0, 0);
    if (t + 1 < TS && quad == 0)
      xv = *(const half8*)&xt[t + 1][l15 * 8];
    BAR();                               // h(t-1) visible
    if (t > 0) {                         // coalesced h(t-1) -> hs1
      float2 cp = *(const float2*)&hb[t & 1][tid * 4];
      *(float2*)&hs1w[(size_t)(t - 1) * 2048 + tid * 4] = cp;
    }
#pragma unroll
    for (int kt = 0; kt < 4; ++kt) {     // conflict-free b128 reads
      half8 ah = *(const half8*)&hb[t & 1][kt * 512 + rbase];
#pragma unroll
      for (int gt = 0; gt < 4; ++gt)
        acc[gt] = __builtin_amdgcn_mfma_f32_16x16x32_f16(ah, bh[kt][gt], acc[gt], 0, 0, 0);
    }
    const int wb = (t + 1) & 1;
#pragma unroll
    for (int r = 0; r < 4; ++r) {
      _Float16 hh = lstm_cell(acc[0][r], acc[1][r], acc[2][r], acc[3][r], c[r]);
      float hr = (float)hh;
      ssum += hr; ssq += hr * hr;
      hb[wb][wbase + r * 8] = hh;
    }
  }
  BAR();                                 // h(127) visible
  {
    float2 cp = *(const float2*)&hb[0][tid * 4];
    *(float2*)&hs1w[(size_t)(TS - 1) * 2048 + tid * 4] = cp;
  }
  float s = ssum, q = ssq;
  s += __shfl_xor(s, 16); s += __shfl_xor(s, 32);
  q += __shfl_xor(q, 16); q += __shfl_xor(q, 32);
  if (quad == 0) {                       // deterministic per-WG partials
    s1part[wg * HID + col] = s;
    s1qpart[wg * HID + col] = q;
  }
}

// ---------------------------------------------------------------------------
// Mid: reduce BN1 partials; w2s = scale-folded Wih2 (fp16); bias2eff.
// ---------------------------------------------------------------------------
__global__ void mid_kernel(const float* __restrict__ s1part, const float* __restrict__ s1qpart,
                           const float* __restrict__ g1, const float* __restrict__ b1,
                           const float* __restrict__ Wih2,
                           const float* __restrict__ bih2, const float* __restrict__ bhh2,
                           _Float16* __restrict__ w2s, float* __restrict__ bias2eff) {
  int bid = blockIdx.x, tid = threadIdx.x;
  if (bid < 768) {                       // w2s: [3][128 k][512 g]; one (inp,k)/block
    int i0 = bid * 256;
    int inp = i0 >> 16, k = (i0 & 65535) >> 9;
    __shared__ float red[65];
    if (tid < 32) {
      red[tid] = s1part[(inp * 32 + tid) * HID + k];
      red[32 + tid] = s1qpart[(inp * 32 + tid) * HID + k];
    }
    __syncthreads();
    if (tid == 0) {
      float sm = 0.0f, sq = 0.0f;
      for (int j = 0; j < 32; ++j) { sm += red[j]; sq += red[32 + j]; }
      float m = sm * INV_N;
      float v = sq * INV_N - m * m;
      red[64] = g1[k] * rsqrtf(v + 1e-5f);
    }
    __syncthreads();
    float sc = red[64];
    int i = i0 + tid, g = i & 511;
    w2s[i] = (_Float16)(sc * Wih2[g * HID + k]);
  } else {                               // bias2eff: [3][512]
    int i = (bid - 768) * 256 + tid;
    int inp = i >> 9, g = i & 511;
    __shared__ float sc[128], sh[128];
    if (tid < 128) {
      float sm = 0.0f, sq = 0.0f;
      for (int j = 0; j < 32; ++j) {
        sm += s1part[(inp * 32 + j) * HID + tid];
        sq += s1qpart[(inp * 32 + j) * HID + tid];
      }
      float m = sm * INV_N;
      float v = sq * INV_N - m * m;
      float s = g1[tid] * rsqrtf(v + 1e-5f);
      sc[tid] = s;
      sh[tid] = b1[tid] - m * s;
    }
    __syncthreads();
    float acc = bih2[g] + bhh2[g];
    for (int h = 0; h < HID; ++h) acc += sh[h] * Wih2[g * HID + h];
    bias2eff[i] = acc;
  }
}

// ---------------------------------------------------------------------------
// LSTM layer 2 (R7-proven step loop). BN2 partials per WG (no atomics).
// ---------------------------------------------------------------------------
__global__ __launch_bounds__(512, 2) void lstm2_kernel(
    const _Float16* __restrict__ hs1,    // [96][128][2048] A-frag order
    const _Float16* __restrict__ w2s,    // [3][128 k][512 g]
    const float* __restrict__ Whh2,
    const float* __restrict__ bias2eff,  // [3][512]
    _Float16* __restrict__ hlast,        // [96][2048] A-frag order
    float* __restrict__ s2part, float* __restrict__ s2qpart) {
  const int wg = blockIdx.x;             // tile 0..95
  const int inp = wg >> 5;
  const int tid = threadIdx.x;
  const int w = tid >> 6;
  const int lane = tid & 63;
  const int l15 = lane & 15;
  const int quad = lane >> 4;
  const int col = w * 16 + l15;
  const int kb = quad * 8;

  __shared__ _Float16 hb[2][2048];
  for (int i = tid; i < 4096; i += 512) ((_Float16*)hb)[i] = (_Float16)0.0f;

  const _Float16* w2sI = w2s + (size_t)inp * HID * NGATE;
  half8 bh[4][4], bxw[4][4];
#pragma unroll
  for (int kt = 0; kt < 4; ++kt)
#pragma unroll
    for (int gt = 0; gt < 4; ++gt) {
      int gcol = gt * 128 + col;
      const float* ph = &Whh2[(size_t)gcol * HID + kt * 32 + kb];
      half8 vh, vx;
#pragma unroll
      for (int j = 0; j < 8; ++j) {
        vh[j] = (_Float16)ph[j];
        vx[j] = w2sI[(kt * 32 + kb + j) * NGATE + gcol];
      }
      bh[kt][gt] = vh;
      bxw[kt][gt] = vx;
    }
  f32x4 biasv[4];
#pragma unroll
  for (int gt = 0; gt < 4; ++gt) {
    float b = bias2eff[inp * NGATE + gt * 128 + col];
    biasv[gt][0] = b; biasv[gt][1] = b; biasv[gt][2] = b; biasv[gt][3] = b;
  }

  const int rbase = (quad * 16 + l15) * 8;
  const int wbase = (w >> 1) * 512 + ((w & 1) * 2 + (l15 >> 3)) * 128 +
                    quad * 32 + (l15 & 7);
  const _Float16* hg = hs1 + (size_t)wg * TS * 2048;

  half8 a2A[4], a2B[4];                  // 2-deep hs1 prefetch (coalesced 16B)
#pragma unroll
  for (int kt = 0; kt < 4; ++kt) {
    a2A[kt] = *(const half8*)&hg[kt * 512 + rbase];
    a2B[kt] = *(const half8*)&hg[(size_t)2048 + kt * 512 + rbase];
  }

  float c[4] = {0, 0, 0, 0};
  float ssum = 0.0f, ssq = 0.0f;

  __syncthreads();                       // hb zero-init visible

  auto step = [&](int t, half8 (&cur)[4]) {
    f32x4 acc[4];
#pragma unroll
    for (int gt = 0; gt < 4; ++gt)
      acc[gt] = __builtin_amdgcn_mfma_f32_16x16x32_f16(cur[0], bxw[0][gt], biasv[gt], 0, 0, 0);
#pragma unroll
    for (int kt = 1; kt < 4; ++kt)
#pragma unroll
      for (int gt = 0; gt < 4; ++gt)
        acc[gt] = __builtin_amdgcn_mfma_f32_16x16x32_f16(cur[kt], bxw[kt][gt], acc[gt], 0, 0, 0);
    if (t + 2 < TS) {                    // prefetch t+2 into regs just consumed
#pragma unroll
      for (int kt = 0; kt < 4; ++kt)
        cur[kt] = *(const half8*)&hg[(size_t)(t + 2) * 2048 + kt * 512 + rbase];
    }
    BAR();                               // h(t-1) visible; vmcnt untouched
#pragma unroll
    for (int kt = 0; kt < 4; ++kt) {
      half8 ah = *(const half8*)&hb[t & 1][kt * 512 + rbase];
#pragma unroll
      for (int gt = 0; gt < 4; ++gt)
        acc[gt] = __builtin_amdgcn_mfma_f32_16x16x32_f16(ah, bh[kt][gt], acc[gt], 0, 0, 0);
    }
    const int wb = (t + 1) & 1;
#pragma unroll
    for (int r = 0; r < 4; ++r) {
      _Float16 hh = lstm_cell(acc[0][r], acc[1][r], acc[2][r], acc[3][r], c[r]);
      float hr = (float)hh;
      ssum += hr; ssq += hr * hr;
      hb[wb][wbase + r * 8] = hh;        // h(127) lands in buffer 0
    }
  };

  for (int t = 0; t < TS; t += 2) {
    step(t, a2A);
    step(t + 1, a2B);
  }

  BAR();                                 // h(127) writes visible
  {
    float2 cp = *(const float2*)&hb[0][tid * 4];
    *(float2*)&hlast[(size_t)wg * 2048 + tid * 4] = cp;
  }
  float s = ssum, q = ssq;
  s += __shfl_xor(s, 16); s += __shfl_xor(s, 32);
  q += __shfl_xor(q, 16); q += __shfl_xor(q, 32);
  if (quad == 0) {                       // deterministic per-WG partials
    s2part[wg * HID + col] = s;
    s2qpart[wg * HID + col] = q;
  }
}

// ---------------------------------------------------------------------------
// Head: reduce BN2 partials; BN2 + FC + L2 normalize. 96 WGs x 256.
// ---------------------------------------------------------------------------
__global__ __launch_bounds__(256, 1) void head_kernel(
    const _Float16* __restrict__ hlast,  // [96][2048] A-frag order
    const float* __restrict__ s2part, const float* __restrict__ s2qpart,
    const float* __restrict__ g2, const float* __restrict__ b2,
    const float* __restrict__ fcW, const float* __restrict__ fcb,
    float* __restrict__ out) {
  const int wg = blockIdx.x;
  const int inp = wg >> 5;
  const int gr0 = wg * 16;
  const int tid = threadIdx.x;

  __shared__ float fcwT[128][132];       // fcwT[h][j] = fcW[j][h]
  __shared__ float bnh[16][132];
  __shared__ float s2[128], sh2[128];
  __shared__ float part[16][16];
  __shared__ float inv[16];

  if (tid < 128) {
    float sm = 0.0f, sq = 0.0f;
    for (int j = 0; j < 32; ++j) {
      sm += s2part[(inp * 32 + j) * HID + tid];
      sq += s2qpart[(inp * 32 + j) * HID + tid];
    }
    float m = sm * INV_N;
    float v = sq * INV_N - m * m;
    float s = g2[tid] * rsqrtf(v + 1e-5f);
    s2[tid] = s; sh2[tid] = b2[tid] - m * s;
  }
  for (int i = tid; i < 16384; i += 256) {
    int j = i >> 7, h = i & 127;
    fcwT[h][j] = fcW[i];
  }
  __syncthreads();
  {
    int row = tid >> 4, c0 = (tid & 15) * 8;
#pragma unroll
    for (int k = 0; k < 8; ++k) {
      int h = c0 + k;
      int ad = ((h >> 5) << 9) + (((h >> 3) & 3) << 7) + (row << 3) + (h & 7);
      bnh[row][h] = (float)hlast[(size_t)wg * 2048 + ad] * s2[h] + sh2[h];
    }
  }
  __syncthreads();
  const int row = tid >> 4, jl = tid & 15;
  float emb[8];
  float sq = 0.0f;
#pragma unroll
  for (int jj = 0; jj < 8; ++jj) {
    int j = jl + jj * 16;
    float acc = fcb[j];
    for (int h = 0; h < HID; ++h) acc += bnh[row][h] * fcwT[h][j];
    emb[jj] = acc; sq += acc * acc;
  }
  part[row][jl] = sq;
  __syncthreads();
  if (tid < 16) {
    float s = 0.0f;
    for (int k = 0; k < 16; ++k) s += part[tid][k];
    inv[tid] = 1.0f / fmaxf(sqrtf(s), 1e-12f);
  }
  __syncthreads();
#pragma unroll
  for (int jj = 0; jj < 8; ++jj)
    out[(size_t)(gr0 + row) * HID + jl + jj * 16] = emb[jj] * inv[row];
}

// ---------------------------------------------------------------------------
extern "C" void kernel_launch(void* const* d_in, const int* in_sizes, int n_in,
                              void* d_out, int out_size, void* d_ws, size_t ws_size,
                              hipStream_t stream) {
  const float* a    = (const float*)d_in[0];
  const float* p    = (const float*)d_in[1];
  const float* nn   = (const float*)d_in[2];
  const float* Wih1 = (const float*)d_in[3];
  const float* Whh1 = (const float*)d_in[4];
  const float* bih1 = (const float*)d_in[5];
  const float* bhh1 = (const float*)d_in[6];
  const float* g1   = (const float*)d_in[7];
  const float* b1   = (const float*)d_in[8];
  const float* Wih2 = (const float*)d_in[9];
  const float* Whh2 = (const float*)d_in[10];
  const float* bih2 = (const float*)d_in[11];
  const float* bhh2 = (const float*)d_in[12];
  const float* g2   = (const float*)d_in[13];
  const float* b2   = (const float*)d_in[14];
  const float* fcW  = (const float*)d_in[15];
  const float* fcb  = (const float*)d_in[16];

  char* ws = (char*)d_ws;
  float* s1part  = (float*)(ws + 0);           // 96*128 f32 = 49152B
  float* s1qpart = (float*)(ws + 49152);       // -> @98304
  float* s2part  = (float*)(ws + 98304);       // -> @147456
  float* s2qpart = (float*)(ws + 147456);      // -> @196608
  _Float16* w2s   = (_Float16*)(ws + 196608);  // 393216B -> @589824
  float* bias2eff = (float*)(ws + 589824);     // 6144B  -> @595968
  _Float16* hlast = (_Float16*)(ws + 595968);  // 393216B -> @989184
  _Float16* hs1   = (_Float16*)(ws + 989184);  // 50331648B -> ~51.3MB total

  // No memset: every workspace byte read in a launch is written earlier in
  // that same launch (harness re-poisons ws to 0xAA between launches).

  lstm1_kernel<<<96, 512, 0, stream>>>(a, p, nn, Wih1, Whh1, bih1, bhh1,
                                       hs1, s1part, s1qpart);
  mid_kernel<<<774, 256, 0, stream>>>(s1part, s1qpart, g1, b1, Wih2, bih2, bhh2,
                                      w2s, bias2eff);
  lstm2_kernel<<<96, 512, 0, stream>>>(hs1, w2s, Whh2, bias2eff,
                                       hlast, s2part, s2qpart);
  head_kernel<<<96, 256, 0, stream>>>(hlast, s2part, s2qpart, g2, b2, fcW, fcb,
                                      (float*)d_out);
}